// Round 1
// baseline (297.560 us; speedup 1.0000x reference)
//
#include <hip/hip_runtime.h>

typedef _Float16 f16;
typedef _Float16 f16x8 __attribute__((ext_vector_type(8)));
typedef float    f32x4 __attribute__((ext_vector_type(4)));

#define NB   8
#define TE   2048
#define TD   2048
#define DIM  256
#define LOG2E 1.44269504088896340736f

#define AS1(p) ((const __attribute__((address_space(1))) void*)(p))
#define AS3(p) ((__attribute__((address_space(3))) void*)(p))

// ---------------- prep 1: fp32 -> f16 (coalesced) ----------------
__global__ __launch_bounds__(256) void cvt_f16_kernel(const float* __restrict__ src,
                                                      f16* __restrict__ dst) {
    int i = (blockIdx.x * 256 + threadIdx.x) * 8;
    float4 a = *(const float4*)(src + i);
    float4 b = *(const float4*)(src + i + 4);
    f16x8 o;
    o[0] = (f16)a.x; o[1] = (f16)a.y; o[2] = (f16)a.z; o[3] = (f16)a.w;
    o[4] = (f16)b.x; o[5] = (f16)b.y; o[6] = (f16)b.z; o[7] = (f16)b.w;
    *(f16x8*)(dst + i) = o;
}

// ---------------- prep 2: enc[b][e][d] fp32 -> enc_t[b][d][e] f16 ----------------
__global__ __launch_bounds__(256) void transpose_kernel(const float* __restrict__ enc,
                                                        f16* __restrict__ enct) {
    __shared__ f16 tile[64][72];   // +8 f16 pad keeps rows 16B-aligned, breaks pow2 stride
    int b  = blockIdx.z;
    int e0 = blockIdx.x * 64;
    int d0 = blockIdx.y * 64;
    int tid = threadIdx.x;
    {
        int e  = tid >> 2;
        int dg = (tid & 3) * 16;
        const float* p = enc + ((size_t)b * TE + e0 + e) * DIM + d0 + dg;
        float4 v0 = *(const float4*)(p);
        float4 v1 = *(const float4*)(p + 4);
        float4 v2 = *(const float4*)(p + 8);
        float4 v3 = *(const float4*)(p + 12);
        f16x8 o0, o1;
        o0[0]=(f16)v0.x; o0[1]=(f16)v0.y; o0[2]=(f16)v0.z; o0[3]=(f16)v0.w;
        o0[4]=(f16)v1.x; o0[5]=(f16)v1.y; o0[6]=(f16)v1.z; o0[7]=(f16)v1.w;
        o1[0]=(f16)v2.x; o1[1]=(f16)v2.y; o1[2]=(f16)v2.z; o1[3]=(f16)v2.w;
        o1[4]=(f16)v3.x; o1[5]=(f16)v3.y; o1[6]=(f16)v3.z; o1[7]=(f16)v3.w;
        *(f16x8*)&tile[e][dg]     = o0;
        *(f16x8*)&tile[e][dg + 8] = o1;
    }
    __syncthreads();
    {
        int d  = tid >> 2;
        int eg = (tid & 3) * 16;
        f16x8 o0, o1;
        #pragma unroll
        for (int ii = 0; ii < 8; ii++) o0[ii] = tile[eg + ii][d];
        #pragma unroll
        for (int ii = 0; ii < 8; ii++) o1[ii] = tile[eg + 8 + ii][d];
        f16* qp = enct + ((size_t)b * DIM + d0 + d) * TE + e0 + eg;
        *(f16x8*)(qp)     = o0;
        *(f16x8*)(qp + 8) = o1;
    }
}

// ---------------- main fused attention ----------------
// grid (16, 8); block 256 = 4 waves: wave = (th<<1)|dh ; th = t-half (64 t), dh = d-half (128 d)
// Per iter (32 encoder rows):
//   QK:  St[e][t] : A = enc (LDS nat, swizzled), B = dec (128 VGPRs, resident)   -> D: col=t=lane&15, row=e=q*4+r
//   softmax over e: in-lane + shfl_xor(16/32); alpha is a per-lane scalar
//   P -> LDS roundtrip (m120 path) -> PV B-operand
//   PV:  ctxT[d][t] : A = enc_t (LDS trans), B = P
#define LDS_NAT 0
#define LDS_TR  16384
#define LDS_P   32768   // 4 waves * 64 t * 80B(stride 40 halfwords)

__global__ __launch_bounds__(256, 1) void attn_kernel(
        const float* __restrict__ dec32,
        const f16*  __restrict__ dec_h,
        const f16*  __restrict__ enc_h,
        const f16*  __restrict__ enc_t,
        float* __restrict__ out) {
    __shared__ char lds[LDS_P + 4 * 5120];  // 53248 B
    const int tid  = threadIdx.x;
    const int lane = tid & 63;
    const int wave = tid >> 6;
    const int th   = wave >> 1;
    const int dh   = wave & 1;
    const int tcol = lane & 15;
    const int q    = lane >> 4;
    const int b    = blockIdx.y;
    const int t0   = blockIdx.x * 128;

    // ---- decoder passthrough: out[..., 0:256] = dec (exact fp32) ----
    {
        const float* dp = dec32 + ((size_t)b * TD + t0) * DIM;
        float*       op = out   + ((size_t)b * TD + t0) * 512;
        #pragma unroll
        for (int i = 0; i < 32; i++) {
            int idx = i * 256 + tid;
            int t = idx >> 6, c = idx & 63;
            float4 v = *(const float4*)(dp + t * DIM + c * 4);
            *(float4*)(op + t * 512 + c * 4) = v;
        }
    }

    // ---- Q fragments (MFMA B-operand: B[k=q*8+j][n=tcol]), resident in regs ----
    f16x8 qf[4][8];   // [tn][ks]  t = t0 + th*64 + tn*16 + tcol ; d = ks*32 + q*8 + j
    {
        const f16* qp = dec_h + ((size_t)b * TD + t0 + th * 64) * DIM;
        #pragma unroll
        for (int tn = 0; tn < 4; tn++)
            #pragma unroll
            for (int ks = 0; ks < 8; ks++)
                qf[tn][ks] = *(const f16x8*)(qp + (size_t)(tn * 16 + tcol) * DIM + ks * 32 + q * 8);
    }

    // ---- staging offsets (global_load_lds: wave-uniform LDS base + lane*16) ----
    const f16* enc_b  = enc_h + (size_t)b * TE * DIM;
    const f16* enct_b = enc_t + (size_t)b * DIM * TE;
    int nat_goff[4], tr_goff[4], nat_loff[4], tr_loff[4];
    #pragma unroll
    for (int i = 0; i < 4; i++) {
        int s = i * 256 + tid;
        int e = s >> 5, cs = s & 31;
        int cg = cs ^ (e & 7);                 // XOR swizzle: conflict-free frag reads
        nat_goff[i] = e * DIM + cg * 8;        // f16 elements, + e0*DIM per iter
        nat_loff[i] = LDS_NAT + (s & ~63) * 16;
        int d = s >> 2, c = s & 3;
        tr_goff[i] = d * TE + c * 8;           // + e0 per iter
        tr_loff[i] = LDS_TR + (s & ~63) * 16;
    }

    // ---- softmax state + accumulators ----
    const f32x4 zero4 = {0.f, 0.f, 0.f, 0.f};
    float m_[4] = {-INFINITY, -INFINITY, -INFINITY, -INFINITY};
    float l_[4] = {0.f, 0.f, 0.f, 0.f};
    f32x4 ctx[8][4];                            // [d-mtile][tn]
    #pragma unroll
    for (int dm = 0; dm < 8; dm++)
        #pragma unroll
        for (int tn = 0; tn < 4; tn++) ctx[dm][tn] = zero4;

    char* pb = lds + LDS_P + wave * 5120;       // P: [64 t][stride 40 halfwords]
    const int e7 = tcol & 7;

    for (int it = 0; it < 64; it++) {
        // ---- stage K(nat, swizzled) + V(trans) tiles for this iter ----
        {
            int e0 = it * 32;
            #pragma unroll
            for (int i = 0; i < 4; i++)
                __builtin_amdgcn_global_load_lds(AS1(enc_b + (size_t)e0 * DIM + nat_goff[i]),
                                                 AS3(lds + nat_loff[i]), 16, 0, 0);
            #pragma unroll
            for (int i = 0; i < 4; i++)
                __builtin_amdgcn_global_load_lds(AS1(enct_b + e0 + tr_goff[i]),
                                                 AS3(lds + tr_loff[i]), 16, 0, 0);
        }
        __syncthreads();   // drains vmcnt: staged tiles complete + visible

        // ---- QK: St[e 32][t 64-slice] ----
        f32x4 st[2][4];
        #pragma unroll
        for (int mt = 0; mt < 2; mt++)
            #pragma unroll
            for (int tn = 0; tn < 4; tn++) st[mt][tn] = zero4;
        #pragma unroll
        for (int ks = 0; ks < 8; ks++) {
            #pragma unroll
            for (int mt = 0; mt < 2; mt++) {
                int e = mt * 16 + tcol;
                f16x8 af = *(const f16x8*)(lds + LDS_NAT + e * 512 + (((ks << 2) | q) ^ e7) * 16);
                #pragma unroll
                for (int tn = 0; tn < 4; tn++)
                    st[mt][tn] = __builtin_amdgcn_mfma_f32_16x16x32_f16(af, qf[tn][ks], st[mt][tn], 0, 0, 0);
            }
        }

        // ---- online softmax over e (rows) + write P ----
        #pragma unroll
        for (int tn = 0; tn < 4; tn++) {
            float mx = st[0][tn][0];
            #pragma unroll
            for (int mt = 0; mt < 2; mt++)
                #pragma unroll
                for (int r = 0; r < 4; r++) mx = fmaxf(mx, st[mt][tn][r]);
            mx = fmaxf(mx, __shfl_xor(mx, 16, 64));
            mx = fmaxf(mx, __shfl_xor(mx, 32, 64));
            float mn = fmaxf(m_[tn], mx);
            float al = exp2f((m_[tn] - mn) * LOG2E);
            m_[tn] = mn;
            float ssum = 0.f;
            char* prow = pb + (tn * 16 + tcol) * 80;
            #pragma unroll
            for (int mt = 0; mt < 2; mt++)
                #pragma unroll
                for (int r = 0; r < 4; r++) {
                    float p = exp2f((st[mt][tn][r] - mn) * LOG2E);
                    ssum += p;
                    *(f16*)(prow + (mt * 16 + q * 4 + r) * 2) = (f16)p;  // P[e][t], e = mt*16+q*4+r
                }
            ssum += __shfl_xor(ssum, 16, 64);
            ssum += __shfl_xor(ssum, 32, 64);
            l_[tn] = l_[tn] * al + ssum;
            #pragma unroll
            for (int dm = 0; dm < 8; dm++) {
                ctx[dm][tn][0] *= al; ctx[dm][tn][1] *= al;
                ctx[dm][tn][2] *= al; ctx[dm][tn][3] *= al;
            }
        }

        // ---- PV: ctxT[d][t] += enc_t * P ----
        f16x8 pf[4];
        #pragma unroll
        for (int tn = 0; tn < 4; tn++)
            pf[tn] = *(const f16x8*)(pb + (tn * 16 + tcol) * 80 + q * 16);  // B[k=e=q*8+j][n=t]
        #pragma unroll
        for (int dm = 0; dm < 8; dm++) {
            int drow = dh * 128 + dm * 16 + tcol;
            f16x8 af = *(const f16x8*)(lds + LDS_TR + drow * 64 + q * 16);  // A[m=d][k=e]
            #pragma unroll
            for (int tn = 0; tn < 4; tn++)
                ctx[dm][tn] = __builtin_amdgcn_mfma_f32_16x16x32_f16(af, pf[tn], ctx[dm][tn], 0, 0, 0);
        }
        __syncthreads();   // all reads done before next iter restages
    }

    // ---- epilogue: out[..., 256:512] = ctx / l ----
    {
        float* ob = out + ((size_t)b * TD + t0 + th * 64) * 512 + 256 + dh * 128;
        #pragma unroll
        for (int tn = 0; tn < 4; tn++) {
            float inv = 1.0f / l_[tn];
            #pragma unroll
            for (int dm = 0; dm < 8; dm++)
                #pragma unroll
                for (int r = 0; r < 4; r++)
                    ob[(size_t)(tn * 16 + tcol) * 512 + dm * 16 + q * 4 + r] = ctx[dm][tn][r] * inv;
        }
    }
}

extern "C" void kernel_launch(void* const* d_in, const int* in_sizes, int n_in,
                              void* d_out, int out_size, void* d_ws, size_t ws_size,
                              hipStream_t stream) {
    (void)in_sizes; (void)n_in;
    const float* enc = (const float*)d_in[0];   // encoder_outputs (8,2048,256) fp32
    const float* dec = (const float*)d_in[1];   // decoder_outputs (8,2048,256) fp32
    float* out = (float*)d_out;                 // (8,2048,512) fp32

    const size_t NELEM = (size_t)NB * TD * DIM;         // 4,194,304
    const size_t HBYTES = NELEM * sizeof(f16);          // 8,388,608
    const size_t WS_NEED = 3 * HBYTES;                  // 25,165,824

    if (ws_size < WS_NEED) {                            // safe fallback: defined output
        hipMemsetAsync(d_out, 0, (size_t)out_size * sizeof(float), stream);
        return;
    }
    f16* dec_h = (f16*)d_ws;
    f16* enc_h = (f16*)((char*)d_ws + HBYTES);
    f16* enc_t = (f16*)((char*)d_ws + 2 * HBYTES);

    cvt_f16_kernel<<<2048, 256, 0, stream>>>(dec, dec_h);
    cvt_f16_kernel<<<2048, 256, 0, stream>>>(enc, enc_h);
    transpose_kernel<<<dim3(32, 4, 8), 256, 0, stream>>>(enc, enc_t);
    attn_kernel<<<dim3(16, 8), 256, 0, stream>>>(dec, dec_h, enc_h, enc_t, out);
}

// Round 2
// 234.186 us; speedup vs baseline: 1.2706x; 1.2706x over previous
//
#include <hip/hip_runtime.h>

typedef _Float16 f16;
typedef _Float16 f16x4 __attribute__((ext_vector_type(4)));
typedef _Float16 f16x8 __attribute__((ext_vector_type(8)));
typedef float    f32x4 __attribute__((ext_vector_type(4)));

#define NB   8
#define TE   2048
#define TD   2048
#define DIM  256
#define NSPLIT 4
#define LOG2E 1.44269504088896340736f

#define AS1(p) ((const __attribute__((address_space(1))) void*)(p))
#define AS3(p) ((__attribute__((address_space(3))) void*)(p))

// ---------------- prep: enc fp32 -> enc_h f16 (same layout) + enc_t f16 (transposed) ----------------
__global__ __launch_bounds__(256) void prep_kernel(const float* __restrict__ enc,
                                                   f16* __restrict__ ench,
                                                   f16* __restrict__ enct) {
    __shared__ f16 tile[64][72];   // +8 pad: 16B-aligned rows, breaks pow2 stride
    int b  = blockIdx.z;
    int e0 = blockIdx.x * 64;
    int d0 = blockIdx.y * 64;
    int tid = threadIdx.x;
    {
        int e  = tid >> 2;
        int dg = (tid & 3) * 16;
        const float* p = enc + ((size_t)b * TE + e0 + e) * DIM + d0 + dg;
        float4 v0 = *(const float4*)(p);
        float4 v1 = *(const float4*)(p + 4);
        float4 v2 = *(const float4*)(p + 8);
        float4 v3 = *(const float4*)(p + 12);
        f16x8 o0, o1;
        o0[0]=(f16)v0.x; o0[1]=(f16)v0.y; o0[2]=(f16)v0.z; o0[3]=(f16)v0.w;
        o0[4]=(f16)v1.x; o0[5]=(f16)v1.y; o0[6]=(f16)v1.z; o0[7]=(f16)v1.w;
        o1[0]=(f16)v2.x; o1[1]=(f16)v2.y; o1[2]=(f16)v2.z; o1[3]=(f16)v2.w;
        o1[4]=(f16)v3.x; o1[5]=(f16)v3.y; o1[6]=(f16)v3.z; o1[7]=(f16)v3.w;
        *(f16x8*)&tile[e][dg]     = o0;
        *(f16x8*)&tile[e][dg + 8] = o1;
        f16* hp = ench + ((size_t)b * TE + e0 + e) * DIM + d0 + dg;   // fused f16 copy
        *(f16x8*)(hp)     = o0;
        *(f16x8*)(hp + 8) = o1;
    }
    __syncthreads();
    {
        int d  = tid >> 2;
        int eg = (tid & 3) * 16;
        f16x8 o0, o1;
        #pragma unroll
        for (int ii = 0; ii < 8; ii++) o0[ii] = tile[eg + ii][d];
        #pragma unroll
        for (int ii = 0; ii < 8; ii++) o1[ii] = tile[eg + 8 + ii][d];
        f16* qp = enct + ((size_t)b * DIM + d0 + d) * TE + e0 + eg;
        *(f16x8*)(qp)     = o0;
        *(f16x8*)(qp + 8) = o1;
    }
}

// ---------------- fused attention (flash over e, optional e-split) ----------------
// block 256 thr = 4 waves: wave = (th<<1)|dh. th: t-half (64 t), dh: d-half (128 d).
// LDS: NAT double-buffered K tile [32e][256d] (XOR-swizzled), TR single V^T tile
// [256d][32e] (issued at iter top, covered by QK phase), P shared per th-pair.
#define LDS_NAT0 0
#define LDS_NAT1 16384
#define LDS_TR   32768
#define LDS_P    49152          // + th*5120 ; total 59392 B

__global__ __launch_bounds__(256, 1) void attn_kernel(
        const float* __restrict__ dec32,
        const f16*  __restrict__ enc_h,
        const f16*  __restrict__ enc_t,
        float* __restrict__ out,
        f16*   __restrict__ ctxp,
        float* __restrict__ m_arr,
        float* __restrict__ l_arr,
        int nsplit) {
    __shared__ char lds[59392];
    const int tid  = threadIdx.x;
    const int lane = tid & 63;
    const int wave = tid >> 6;
    const int th   = wave >> 1;
    const int dh   = wave & 1;
    const int tcol = lane & 15;
    const int q    = lane >> 4;

    // XCD-aware swizzle (split mode): the 16 t-blocks sharing (b, e-range) -> one XCD
    int xb, b, z;
    if (nsplit == NSPLIT) {
        int fid = blockIdx.x + 16 * (blockIdx.y + 8 * blockIdx.z);
        int c = fid & 7, j = fid >> 3;
        int p = c * 4 + (j >> 4);
        xb = j & 15; b = p & 7; z = p >> 3;
    } else { xb = blockIdx.x; b = blockIdx.y; z = 0; }
    const int t0    = xb * 128;
    const int iters = (TE / 32) / nsplit;
    const int e_base = z * (TE / nsplit);

    const f16* enc_b  = enc_h + (size_t)b * TE * DIM;
    const f16* enct_b = enc_t + (size_t)b * DIM * TE;

    // staging offsets (global_load_lds: wave-uniform LDS base + lane*16)
    int nat_goff[4], tr_goff[4], nat_loff[4], tr_loff[4];
    #pragma unroll
    for (int i = 0; i < 4; i++) {
        int s = i * 256 + tid;
        int e = s >> 5, cs = s & 31;
        nat_goff[i] = e * DIM + (cs ^ (e & 7)) * 8;   // XOR chunk swizzle
        nat_loff[i] = (s & ~63) * 16;
        int d = s >> 2, c = s & 3;
        tr_goff[i] = d * TE + c * 8;
        tr_loff[i] = (s & ~63) * 16;
    }

    // preload NAT(0); Q-build overlaps its latency
    #pragma unroll
    for (int i = 0; i < 4; i++)
        __builtin_amdgcn_global_load_lds(AS1(enc_b + (size_t)e_base * DIM + nat_goff[i]),
                                         AS3(lds + LDS_NAT0 + nat_loff[i]), 16, 0, 0);

    // monolithic mode: decoder passthrough here
    if (nsplit == 1) {
        const float* dp = dec32 + ((size_t)b * TD + t0) * DIM;
        float*       op = out   + ((size_t)b * TD + t0) * 512;
        #pragma unroll
        for (int i = 0; i < 32; i++) {
            int idx = i * 256 + tid;
            int t = idx >> 6, c = idx & 63;
            float4 v = *(const float4*)(dp + t * DIM + c * 4);
            *(float4*)(op + t * 512 + c * 4) = v;
        }
    }

    // Q fragments from fp32 dec (B-operand: B[k=q*8+j][n=tcol]), resident in regs
    f16x8 qf[4][8];
    {
        const float* qp = dec32 + ((size_t)b * TD + t0 + th * 64) * DIM;
        #pragma unroll
        for (int tn = 0; tn < 4; tn++)
            #pragma unroll
            for (int ks = 0; ks < 8; ks++) {
                const float* p = qp + (size_t)(tn * 16 + tcol) * DIM + ks * 32 + q * 8;
                float4 u = *(const float4*)(p);
                float4 v = *(const float4*)(p + 4);
                f16x8 o;
                o[0]=(f16)u.x; o[1]=(f16)u.y; o[2]=(f16)u.z; o[3]=(f16)u.w;
                o[4]=(f16)v.x; o[5]=(f16)v.y; o[6]=(f16)v.z; o[7]=(f16)v.w;
                qf[tn][ks] = o;
            }
    }

    const f32x4 zero4 = {0.f, 0.f, 0.f, 0.f};
    float m_[4] = {-INFINITY, -INFINITY, -INFINITY, -INFINITY};
    float l_[4] = {0.f, 0.f, 0.f, 0.f};
    f32x4 ctx[8][4];
    #pragma unroll
    for (int dm = 0; dm < 8; dm++)
        #pragma unroll
        for (int tn = 0; tn < 4; tn++) ctx[dm][tn] = zero4;

    char* pb = lds + LDS_P + th * 5120;   // P[64 t][stride 40 halfwords], shared dh-pair
    const int e7 = tcol & 7;

    __syncthreads();   // NAT(0) visible

    for (int it = 0; it < iters; it++) {
        const int natc = (it & 1) ? LDS_NAT1 : LDS_NAT0;
        const int e0   = e_base + it * 32;

        // issue TR(it) (consumed after mid barrier) + prefetch NAT(it+1)
        #pragma unroll
        for (int i = 0; i < 4; i++)
            __builtin_amdgcn_global_load_lds(AS1(enct_b + e0 + tr_goff[i]),
                                             AS3(lds + LDS_TR + tr_loff[i]), 16, 0, 0);
        if (it + 1 < iters) {
            const int natn = (it & 1) ? LDS_NAT0 : LDS_NAT1;
            #pragma unroll
            for (int i = 0; i < 4; i++)
                __builtin_amdgcn_global_load_lds(AS1(enc_b + (size_t)(e0 + 32) * DIM + nat_goff[i]),
                                                 AS3(lds + natn + nat_loff[i]), 16, 0, 0);
        }

        // ---- QK: St[e 32][t 64-slice] ----
        f32x4 st[2][4];
        #pragma unroll
        for (int mt = 0; mt < 2; mt++)
            #pragma unroll
            for (int tn = 0; tn < 4; tn++) st[mt][tn] = zero4;
        #pragma unroll
        for (int ks = 0; ks < 8; ks++) {
            #pragma unroll
            for (int mt = 0; mt < 2; mt++) {
                int e = mt * 16 + tcol;
                f16x8 af = *(const f16x8*)(lds + natc + e * 512 + (((ks << 2) | q) ^ e7) * 16);
                #pragma unroll
                for (int tn = 0; tn < 4; tn++)
                    st[mt][tn] = __builtin_amdgcn_mfma_f32_16x16x32_f16(af, qf[tn][ks], st[mt][tn], 0, 0, 0);
            }
        }

        // ---- online softmax over e + vectorized P write (dh==0 only; shared buffer) ----
        #pragma unroll
        for (int tn = 0; tn < 4; tn++) {
            float mx = st[0][tn][0];
            #pragma unroll
            for (int mt = 0; mt < 2; mt++)
                #pragma unroll
                for (int r = 0; r < 4; r++) mx = fmaxf(mx, st[mt][tn][r]);
            mx = fmaxf(mx, __shfl_xor(mx, 16, 64));
            mx = fmaxf(mx, __shfl_xor(mx, 32, 64));
            float mn = fmaxf(m_[tn], mx);
            bool bumped = mn > m_[tn];
            float al = exp2f((m_[tn] - mn) * LOG2E);
            m_[tn] = mn;
            float ssum = 0.f;
            char* prow = pb + (tn * 16 + tcol) * 80;
            #pragma unroll
            for (int mt = 0; mt < 2; mt++) {
                f16x4 pv;
                #pragma unroll
                for (int r = 0; r < 4; r++) {
                    float p = exp2f((st[mt][tn][r] - mn) * LOG2E);
                    ssum += p;
                    pv[r] = (f16)p;
                }
                if (dh == 0) *(f16x4*)(prow + mt * 32 + q * 8) = pv;   // e = mt*16+q*4..+4
            }
            ssum += __shfl_xor(ssum, 16, 64);
            ssum += __shfl_xor(ssum, 32, 64);
            l_[tn] = l_[tn] * al + ssum;
            if (__any(bumped)) {   // skip 32 v_pk muls when running max unchanged
                #pragma unroll
                for (int dm = 0; dm < 8; dm++) {
                    ctx[dm][tn][0] *= al; ctx[dm][tn][1] *= al;
                    ctx[dm][tn][2] *= al; ctx[dm][tn][3] *= al;
                }
            }
        }

        __syncthreads();   // TR(it) + P visible (also drains NAT prefetch early - fine)

        // ---- PV: ctxT[d][t] += enc_t * P ----
        f16x8 pf[4];
        #pragma unroll
        for (int tn = 0; tn < 4; tn++)
            pf[tn] = *(const f16x8*)(pb + (tn * 16 + tcol) * 80 + q * 16);
        #pragma unroll
        for (int dm = 0; dm < 8; dm++) {
            int drow = dh * 128 + dm * 16 + tcol;
            f16x8 af = *(const f16x8*)(lds + LDS_TR + drow * 64 + q * 16);
            #pragma unroll
            for (int tn = 0; tn < 4; tn++)
                ctx[dm][tn] = __builtin_amdgcn_mfma_f32_16x16x32_f16(af, pf[tn], ctx[dm][tn], 0, 0, 0);
        }

        __syncthreads();   // TR/P reads done before next iter overwrites
    }

    // ---- epilogue ----
    if (nsplit > 1) {
        size_t rowbase = (size_t)(z * NB + b) * TD + t0 + th * 64;
        #pragma unroll
        for (int tn = 0; tn < 4; tn++) {
            size_t rb = (rowbase + tn * 16 + tcol) * DIM + dh * 128;
            #pragma unroll
            for (int dm = 0; dm < 8; dm++) {
                f16x4 cv;
                #pragma unroll
                for (int r = 0; r < 4; r++) cv[r] = (f16)ctx[dm][tn][r];
                *(f16x4*)(ctxp + rb + dm * 16 + q * 4) = cv;
            }
        }
        if (dh == 0 && lane < 16) {
            int mi = (z * NB + b) * TD + t0 + th * 64 + lane;
            #pragma unroll
            for (int tn = 0; tn < 4; tn++) {
                m_arr[mi + tn * 16] = m_[tn];
                l_arr[mi + tn * 16] = l_[tn];
            }
        }
    } else {
        float* ob = out + ((size_t)b * TD + t0 + th * 64) * 512 + 256 + dh * 128;
        #pragma unroll
        for (int tn = 0; tn < 4; tn++) {
            float inv = 1.0f / l_[tn];
            #pragma unroll
            for (int dm = 0; dm < 8; dm++)
                #pragma unroll
                for (int r = 0; r < 4; r++)
                    ob[(size_t)(tn * 16 + tcol) * 512 + dm * 16 + q * 4 + r] = ctx[dm][tn][r] * inv;
        }
    }
}

// ---------------- combine: merge NSPLIT partials + decoder passthrough ----------------
__global__ __launch_bounds__(256) void combine_kernel(const float* __restrict__ dec32,
        const f16* __restrict__ ctxp, const float* __restrict__ m_arr,
        const float* __restrict__ l_arr, float* __restrict__ out) {
    int idx  = blockIdx.x * 256 + threadIdx.x;
    int trow = idx >> 5;              // b*TD + t
    int dg   = (idx & 31) * 8;
    float m0[NSPLIT], l0[NSPLIT], M = -INFINITY;
    #pragma unroll
    for (int s = 0; s < NSPLIT; s++) {
        m0[s] = m_arr[s * (NB * TD) + trow];
        l0[s] = l_arr[s * (NB * TD) + trow];
        M = fmaxf(M, m0[s]);
    }
    float L = 0.f, w[NSPLIT];
    #pragma unroll
    for (int s = 0; s < NSPLIT; s++) {
        w[s] = exp2f((m0[s] - M) * LOG2E);
        L += l0[s] * w[s];
    }
    float invL = 1.0f / L;
    float acc[8] = {0.f,0.f,0.f,0.f,0.f,0.f,0.f,0.f};
    #pragma unroll
    for (int s = 0; s < NSPLIT; s++) {
        f16x8 v = *(const f16x8*)(ctxp + ((size_t)s * (NB * TD) + trow) * DIM + dg);
        float ws = w[s] * invL;
        #pragma unroll
        for (int j = 0; j < 8; j++) acc[j] += ws * (float)v[j];
    }
    float4 d0 = *(const float4*)(dec32 + (size_t)trow * DIM + dg);
    float4 d1 = *(const float4*)(dec32 + (size_t)trow * DIM + dg + 4);
    float* ob = out + (size_t)trow * 512;
    *(float4*)(ob + dg)     = d0;
    *(float4*)(ob + dg + 4) = d1;
    float4 c0, c1;
    c0.x=acc[0]; c0.y=acc[1]; c0.z=acc[2]; c0.w=acc[3];
    c1.x=acc[4]; c1.y=acc[5]; c1.z=acc[6]; c1.w=acc[7];
    *(float4*)(ob + 256 + dg)     = c0;
    *(float4*)(ob + 256 + dg + 4) = c1;
}

extern "C" void kernel_launch(void* const* d_in, const int* in_sizes, int n_in,
                              void* d_out, int out_size, void* d_ws, size_t ws_size,
                              hipStream_t stream) {
    (void)in_sizes; (void)n_in;
    const float* enc = (const float*)d_in[0];
    const float* dec = (const float*)d_in[1];
    float* out = (float*)d_out;

    const size_t HB    = (size_t)NB * TE * DIM * 2;            // 8,388,608
    const size_t CTXPB = (size_t)NSPLIT * NB * TD * DIM * 2;   // 33,554,432
    const size_t MLB   = (size_t)NSPLIT * NB * TD * 4;         // 1,048,576 * ... = 262,144? (4*8*2048*4)
    const size_t NEED4 = 2 * HB + CTXPB + 2 * MLB;             // ~50.9 MB
    const size_t NEED1 = 2 * HB;                               // 16.8 MB

    if (ws_size < NEED1) {
        hipMemsetAsync(d_out, 0, (size_t)out_size * sizeof(float), stream);
        return;
    }
    int nsplit = (ws_size >= NEED4) ? NSPLIT : 1;

    f16*   enc_h = (f16*)d_ws;
    f16*   enc_t = (f16*)((char*)d_ws + HB);
    f16*   ctxp  = (f16*)((char*)d_ws + 2 * HB);
    float* m_arr = (float*)((char*)d_ws + 2 * HB + CTXPB);
    float* l_arr = (float*)((char*)d_ws + 2 * HB + CTXPB + MLB);

    prep_kernel<<<dim3(32, 4, 8), 256, 0, stream>>>(enc, enc_h, enc_t);
    attn_kernel<<<dim3(16, 8, nsplit), 256, 0, stream>>>(dec, enc_h, enc_t, out,
                                                         ctxp, m_arr, l_arr, nsplit);
    if (nsplit == NSPLIT)
        combine_kernel<<<2048, 256, 0, stream>>>(dec, ctxp, m_arr, l_arr, out);
}

// Round 3
// 172.519 us; speedup vs baseline: 1.7248x; 1.3575x over previous
//
#include <hip/hip_runtime.h>

typedef _Float16 f16;
typedef _Float16 f16x4 __attribute__((ext_vector_type(4)));
typedef _Float16 f16x8 __attribute__((ext_vector_type(8)));
typedef float    f32x4 __attribute__((ext_vector_type(4)));

#define NB   8
#define TE   2048
#define TD   2048
#define DIM  256
#define NSPLIT 4
#define LOG2E 1.44269504088896340736f

#define AS1(p) ((const __attribute__((address_space(1))) void*)(p))
#define AS3(p) ((__attribute__((address_space(3))) void*)(p))

// ---------------- prep: enc fp32 -> enc_h f16 (same layout) + enc_t f16 (transposed) ----------------
__global__ __launch_bounds__(256) void prep_kernel(const float* __restrict__ enc,
                                                   f16* __restrict__ ench,
                                                   f16* __restrict__ enct) {
    __shared__ f16 tile[64][72];
    int b  = blockIdx.z;
    int e0 = blockIdx.x * 64;
    int d0 = blockIdx.y * 64;
    int tid = threadIdx.x;
    {
        int e  = tid >> 2;
        int dg = (tid & 3) * 16;
        const float* p = enc + ((size_t)b * TE + e0 + e) * DIM + d0 + dg;
        float4 v0 = *(const float4*)(p);
        float4 v1 = *(const float4*)(p + 4);
        float4 v2 = *(const float4*)(p + 8);
        float4 v3 = *(const float4*)(p + 12);
        f16x8 o0, o1;
        o0[0]=(f16)v0.x; o0[1]=(f16)v0.y; o0[2]=(f16)v0.z; o0[3]=(f16)v0.w;
        o0[4]=(f16)v1.x; o0[5]=(f16)v1.y; o0[6]=(f16)v1.z; o0[7]=(f16)v1.w;
        o1[0]=(f16)v2.x; o1[1]=(f16)v2.y; o1[2]=(f16)v2.z; o1[3]=(f16)v2.w;
        o1[4]=(f16)v3.x; o1[5]=(f16)v3.y; o1[6]=(f16)v3.z; o1[7]=(f16)v3.w;
        *(f16x8*)&tile[e][dg]     = o0;
        *(f16x8*)&tile[e][dg + 8] = o1;
        f16* hp = ench + ((size_t)b * TE + e0 + e) * DIM + d0 + dg;
        *(f16x8*)(hp)     = o0;
        *(f16x8*)(hp + 8) = o1;
    }
    __syncthreads();
    {
        int d  = tid >> 2;
        int eg = (tid & 3) * 16;
        f16x8 o0, o1;
        #pragma unroll
        for (int ii = 0; ii < 8; ii++) o0[ii] = tile[eg + ii][d];
        #pragma unroll
        for (int ii = 0; ii < 8; ii++) o1[ii] = tile[eg + 8 + ii][d];
        f16* qp = enct + ((size_t)b * DIM + d0 + d) * TE + e0 + eg;
        *(f16x8*)(qp)     = o0;
        *(f16x8*)(qp + 8) = o1;
    }
}

// ---------------- fused attention (flash over e, e-split) ----------------
// block 256 thr = 4 waves: wave = (th<<1)|dh. th: t-slice of 32, dh: d-half of 128.
// t-tile per block = 64. Register diet (qf 64 V, ctx+lsum 72 acc) + launch_bounds(256,2)
// -> 2 blocks/CU so barrier drains of one block overlap the other's MFMA.
// l accumulated via ones-row PV MFMA (no ssum shuffles).
#define LDS_NAT0 0
#define LDS_NAT1 16384
#define LDS_TR   32768
#define LDS_P    49152          // + th*2560 ; total 54272 B

__global__ __launch_bounds__(256, 2) void attn_kernel(
        const float* __restrict__ dec32,
        const f16*  __restrict__ enc_h,
        const f16*  __restrict__ enc_t,
        float* __restrict__ out,
        f16*   __restrict__ ctxp,
        float* __restrict__ m_arr,
        float* __restrict__ l_arr,
        int nsplit) {
    __shared__ char lds[54272];
    const int tid  = threadIdx.x;
    const int lane = tid & 63;
    const int wave = tid >> 6;
    const int th   = wave >> 1;   // 0..1 : t-slice of 32
    const int dh   = wave & 1;    // 0..1 : d-half of 128
    const int tcol = lane & 15;
    const int q    = lane >> 4;

    // XCD-aware swizzle (split mode): 32 t-blocks sharing (b, e-range) -> one XCD
    int xb, b, z;
    if (nsplit == NSPLIT) {
        int fid = blockIdx.x + 32 * (blockIdx.y + 8 * blockIdx.z);
        int c = fid & 7, j = fid >> 3;
        int p = c * 4 + (j >> 5);
        xb = j & 31; b = p & 7; z = p >> 3;
    } else { xb = blockIdx.x; b = blockIdx.y; z = 0; }
    const int t0     = xb * 64;
    const int iters  = (TE / 32) / nsplit;
    const int e_base = z * (TE / nsplit);

    const f16* enc_b  = enc_h + (size_t)b * TE * DIM;
    const f16* enct_b = enc_t + (size_t)b * DIM * TE;

    // staging offsets (global_load_lds: wave-uniform LDS base + lane*16)
    int nat_goff[4], tr_goff[4], nat_loff[4], tr_loff[4];
    #pragma unroll
    for (int i = 0; i < 4; i++) {
        int s = i * 256 + tid;
        int e = s >> 5, cs = s & 31;
        nat_goff[i] = e * DIM + (cs ^ (e & 7)) * 8;        // XOR chunk swizzle (QK reads)
        nat_loff[i] = (s & ~63) * 16;
        int d = s >> 2, c = s & 3;
        tr_goff[i] = d * TE + (c ^ ((d >> 1) & 3)) * 8;    // XOR chunk swizzle (PV reads 2-way)
        tr_loff[i] = (s & ~63) * 16;
    }

    // preload NAT(0); Q-build overlaps its latency
    #pragma unroll
    for (int i = 0; i < 4; i++)
        __builtin_amdgcn_global_load_lds(AS1(enc_b + (size_t)e_base * DIM + nat_goff[i]),
                                         AS3(lds + LDS_NAT0 + nat_loff[i]), 16, 0, 0);

    // monolithic fallback: decoder passthrough here
    if (nsplit == 1) {
        const float* dp = dec32 + ((size_t)b * TD + t0) * DIM;
        float*       op = out   + ((size_t)b * TD + t0) * 512;
        #pragma unroll
        for (int i = 0; i < 16; i++) {
            int idx = i * 256 + tid;
            int t = idx >> 6, c = idx & 63;
            float4 v = *(const float4*)(dp + t * DIM + c * 4);
            *(float4*)(op + t * 512 + c * 4) = v;
        }
    }

    // Q fragments from fp32 dec (B-operand: B[k=q*8+j][n=tcol]), resident in regs
    f16x8 qf[2][8];
    {
        const float* qp = dec32 + ((size_t)b * TD + t0 + th * 32) * DIM;
        #pragma unroll
        for (int tn = 0; tn < 2; tn++)
            #pragma unroll
            for (int ks = 0; ks < 8; ks++) {
                const float* p = qp + (size_t)(tn * 16 + tcol) * DIM + ks * 32 + q * 8;
                float4 u = *(const float4*)(p);
                float4 v = *(const float4*)(p + 4);
                f16x8 o;
                o[0]=(f16)u.x; o[1]=(f16)u.y; o[2]=(f16)u.z; o[3]=(f16)u.w;
                o[4]=(f16)v.x; o[5]=(f16)v.y; o[6]=(f16)v.z; o[7]=(f16)v.w;
                qf[tn][ks] = o;
            }
    }

    f16x8 ones;
    #pragma unroll
    for (int j = 0; j < 8; j++) ones[j] = (f16)1.0f;

    const f32x4 zero4 = {0.f, 0.f, 0.f, 0.f};
    float m_[2] = {-INFINITY, -INFINITY};
    f32x4 lsum[2] = {zero4, zero4};     // l via ones-row MFMA
    f32x4 ctx[8][2];
    #pragma unroll
    for (int dm = 0; dm < 8; dm++)
        #pragma unroll
        for (int tn = 0; tn < 2; tn++) ctx[dm][tn] = zero4;

    char* pb = lds + LDS_P + th * 2560;   // P[32 t][stride 40 halfwords], shared dh-pair
    const int e7 = tcol & 7;
    const int trsw = (tcol >> 1) & 3;

    __syncthreads();   // NAT(0) visible

    for (int it = 0; it < iters; it++) {
        const int natc = (it & 1) ? LDS_NAT1 : LDS_NAT0;
        const int e0   = e_base + it * 32;

        // issue TR(it) at top (consumed after mid barrier; covered by QK+softmax)
        #pragma unroll
        for (int i = 0; i < 4; i++)
            __builtin_amdgcn_global_load_lds(AS1(enct_b + e0 + tr_goff[i]),
                                             AS3(lds + LDS_TR + tr_loff[i]), 16, 0, 0);

        // ---- QK: St[e 32][t 32-slice] ----
        f32x4 st[2][2];
        #pragma unroll
        for (int mt = 0; mt < 2; mt++)
            #pragma unroll
            for (int tn = 0; tn < 2; tn++) st[mt][tn] = zero4;
        #pragma unroll
        for (int ks = 0; ks < 8; ks++) {
            #pragma unroll
            for (int mt = 0; mt < 2; mt++) {
                int e = mt * 16 + tcol;
                f16x8 af = *(const f16x8*)(lds + natc + e * 512 + (((ks << 2) | q) ^ e7) * 16);
                #pragma unroll
                for (int tn = 0; tn < 2; tn++)
                    st[mt][tn] = __builtin_amdgcn_mfma_f32_16x16x32_f16(af, qf[tn][ks], st[mt][tn], 0, 0, 0);
            }
        }

        // ---- online softmax over e + P write (dh==0 only; shared buffer) ----
        #pragma unroll
        for (int tn = 0; tn < 2; tn++) {
            float mx = fmaxf(fmaxf(fmaxf(st[0][tn][0], st[0][tn][1]), fmaxf(st[0][tn][2], st[0][tn][3])),
                             fmaxf(fmaxf(st[1][tn][0], st[1][tn][1]), fmaxf(st[1][tn][2], st[1][tn][3])));
            mx = fmaxf(mx, __shfl_xor(mx, 16, 64));
            mx = fmaxf(mx, __shfl_xor(mx, 32, 64));
            float mn = fmaxf(m_[tn], mx);
            bool bumped = mn > m_[tn];
            float al = __builtin_amdgcn_exp2f((m_[tn] - mn) * LOG2E);
            m_[tn] = mn;
            char* prow = pb + (tn * 16 + tcol) * 80;
            #pragma unroll
            for (int mt = 0; mt < 2; mt++) {
                f16x4 pv;
                #pragma unroll
                for (int r = 0; r < 4; r++)
                    pv[r] = (f16)__builtin_amdgcn_exp2f((st[mt][tn][r] - mn) * LOG2E);
                if (dh == 0) *(f16x4*)(prow + mt * 32 + q * 8) = pv;   // e = mt*16+q*4..+4
            }
            if (__any(bumped)) {
                lsum[tn][0] *= al; lsum[tn][1] *= al; lsum[tn][2] *= al; lsum[tn][3] *= al;
                #pragma unroll
                for (int dm = 0; dm < 8; dm++) {
                    ctx[dm][tn][0] *= al; ctx[dm][tn][1] *= al;
                    ctx[dm][tn][2] *= al; ctx[dm][tn][3] *= al;
                }
            }
        }

        __syncthreads();   // TR(it) + P visible

        // prefetch NAT(it+1) now (drained at END barrier, covered by PV)
        if (it + 1 < iters) {
            const int natn = (it & 1) ? LDS_NAT0 : LDS_NAT1;
            #pragma unroll
            for (int i = 0; i < 4; i++)
                __builtin_amdgcn_global_load_lds(AS1(enc_b + (size_t)(e0 + 32) * DIM + nat_goff[i]),
                                                 AS3(lds + natn + nat_loff[i]), 16, 0, 0);
        }

        // ---- PV: ctxT[d][t] += enc_t * P ;  l via ones row ----
        f16x8 pf[2];
        #pragma unroll
        for (int tn = 0; tn < 2; tn++)
            pf[tn] = *(const f16x8*)(pb + (tn * 16 + tcol) * 80 + q * 16);
        #pragma unroll
        for (int tn = 0; tn < 2; tn++)
            lsum[tn] = __builtin_amdgcn_mfma_f32_16x16x32_f16(ones, pf[tn], lsum[tn], 0, 0, 0);
        #pragma unroll
        for (int dm = 0; dm < 8; dm++) {
            int drow = dh * 128 + dm * 16 + tcol;
            f16x8 af = *(const f16x8*)(lds + LDS_TR + drow * 64 + (q ^ trsw) * 16);
            #pragma unroll
            for (int tn = 0; tn < 2; tn++)
                ctx[dm][tn] = __builtin_amdgcn_mfma_f32_16x16x32_f16(af, pf[tn], ctx[dm][tn], 0, 0, 0);
        }

        __syncthreads();   // TR/P reads done + NAT(it+1) drained before next iter
    }

    // ---- epilogue ----
    if (nsplit > 1) {
        size_t rowbase = (size_t)(z * NB + b) * TD + t0 + th * 32;
        #pragma unroll
        for (int tn = 0; tn < 2; tn++) {
            float inv = 1.0f / lsum[tn][0];
            size_t rb = (rowbase + tn * 16 + tcol) * DIM + dh * 128;
            #pragma unroll
            for (int dm = 0; dm < 8; dm++) {
                f16x4 cv;
                #pragma unroll
                for (int r = 0; r < 4; r++) cv[r] = (f16)(ctx[dm][tn][r] * inv);
                *(f16x4*)(ctxp + rb + dm * 16 + q * 4) = cv;
            }
        }
        if (dh == 0 && lane < 16) {
            int mi = (z * NB + b) * TD + t0 + th * 32 + lane;
            #pragma unroll
            for (int tn = 0; tn < 2; tn++) {
                m_arr[mi + tn * 16] = m_[tn];
                l_arr[mi + tn * 16] = lsum[tn][0];
            }
        }
    } else {
        float* ob = out + ((size_t)b * TD + t0 + th * 32) * 512 + 256 + dh * 128;
        #pragma unroll
        for (int tn = 0; tn < 2; tn++) {
            float inv = 1.0f / lsum[tn][0];
            #pragma unroll
            for (int dm = 0; dm < 8; dm++)
                #pragma unroll
                for (int r = 0; r < 4; r++)
                    ob[(size_t)(tn * 16 + tcol) * 512 + dm * 16 + q * 4 + r] = ctx[dm][tn][r] * inv;
        }
    }
}

// ---------------- combine: merge NSPLIT normalized partials + decoder passthrough ----------------
__global__ __launch_bounds__(256) void combine_kernel(const float* __restrict__ dec32,
        const f16* __restrict__ ctxp, const float* __restrict__ m_arr,
        const float* __restrict__ l_arr, float* __restrict__ out) {
    int idx  = blockIdx.x * 256 + threadIdx.x;
    int trow = idx >> 5;              // b*TD + t
    int dg   = (idx & 31) * 8;
    float m0[NSPLIT], l0[NSPLIT], M = -INFINITY;
    #pragma unroll
    for (int s = 0; s < NSPLIT; s++) {
        m0[s] = m_arr[s * (NB * TD) + trow];
        l0[s] = l_arr[s * (NB * TD) + trow];
        M = fmaxf(M, m0[s]);
    }
    float L = 0.f, w[NSPLIT];
    #pragma unroll
    for (int s = 0; s < NSPLIT; s++) {
        w[s] = __builtin_amdgcn_exp2f((m0[s] - M) * LOG2E) * l0[s];
        L += w[s];
    }
    float invL = 1.0f / L;
    float acc[8] = {0.f,0.f,0.f,0.f,0.f,0.f,0.f,0.f};
    #pragma unroll
    for (int s = 0; s < NSPLIT; s++) {
        f16x8 v = *(const f16x8*)(ctxp + ((size_t)s * (NB * TD) + trow) * DIM + dg);
        float ws = w[s] * invL;
        #pragma unroll
        for (int j = 0; j < 8; j++) acc[j] += ws * (float)v[j];
    }
    float4 d0 = *(const float4*)(dec32 + (size_t)trow * DIM + dg);
    float4 d1 = *(const float4*)(dec32 + (size_t)trow * DIM + dg + 4);
    float* ob = out + (size_t)trow * 512;
    *(float4*)(ob + dg)     = d0;
    *(float4*)(ob + dg + 4) = d1;
    float4 c0, c1;
    c0.x=acc[0]; c0.y=acc[1]; c0.z=acc[2]; c0.w=acc[3];
    c1.x=acc[4]; c1.y=acc[5]; c1.z=acc[6]; c1.w=acc[7];
    *(float4*)(ob + 256 + dg)     = c0;
    *(float4*)(ob + 256 + dg + 4) = c1;
}

extern "C" void kernel_launch(void* const* d_in, const int* in_sizes, int n_in,
                              void* d_out, int out_size, void* d_ws, size_t ws_size,
                              hipStream_t stream) {
    (void)in_sizes; (void)n_in;
    const float* enc = (const float*)d_in[0];
    const float* dec = (const float*)d_in[1];
    float* out = (float*)d_out;

    const size_t HB    = (size_t)NB * TE * DIM * 2;            // 8,388,608
    const size_t CTXPB = (size_t)NSPLIT * NB * TD * DIM * 2;   // 33,554,432
    const size_t MLB   = (size_t)NSPLIT * NB * TD * 4;         // 262,144
    const size_t NEED4 = 2 * HB + CTXPB + 2 * MLB;             // ~50.9 MB
    const size_t NEED1 = 2 * HB;

    if (ws_size < NEED1) {
        hipMemsetAsync(d_out, 0, (size_t)out_size * sizeof(float), stream);
        return;
    }
    int nsplit = (ws_size >= NEED4) ? NSPLIT : 1;

    f16*   enc_h = (f16*)d_ws;
    f16*   enc_t = (f16*)((char*)d_ws + HB);
    f16*   ctxp  = (f16*)((char*)d_ws + 2 * HB);
    float* m_arr = (float*)((char*)d_ws + 2 * HB + CTXPB);
    float* l_arr = (float*)((char*)d_ws + 2 * HB + CTXPB + MLB);

    prep_kernel<<<dim3(32, 4, 8), 256, 0, stream>>>(enc, enc_h, enc_t);
    attn_kernel<<<dim3(32, 8, nsplit), 256, 0, stream>>>(dec, enc_h, enc_t, out,
                                                         ctxp, m_arr, l_arr, nsplit);
    if (nsplit == NSPLIT)
        combine_kernel<<<2048, 256, 0, stream>>>(dec, ctxp, m_arr, l_arr, out);
}